// Round 1
// baseline (655.118 us; speedup 1.0000x reference)
//
#include <hip/hip_runtime.h>

#define ALPHA_F 32.0f
#define EPS_F 1e-8f
#define NEG_SLOPE_F 0.01f

#define D_IN 4096
#define D_OUT 4096
#define RNK 16
#define N_ROWS 16384
#define ROWS_PER_BLOCK 16
#define THREADS 256

// One block = 16 rows (4 waves x 4 rows/wave).
// Phase A: new_x = x @ W_a   (x coalesced float4, W_a from L2)
// Stage 2: h_t1 = h@Wc + new_x@Wd + h; min-max norm over R; leaky; u = 32*(new_x+act)
// Phase B: y = u @ W_b       (W_b coalesced float4, y coalesced float4 stores)
__global__ __launch_bounds__(THREADS) void ssm_lora_fused(
    const float* __restrict__ x,
    const float* __restrict__ h_t,
    const float* __restrict__ Wa,
    const float* __restrict__ Wb,
    const float* __restrict__ Wc,
    const float* __restrict__ Wd,
    float* __restrict__ y)
{
    // stride 68 floats (272B): 16 writers at 272B stride -> 2-way bank alias (free)
    __shared__ float red[4][16][68];
    __shared__ float lds_nx[16][16];
    __shared__ float lds_u[16][16];

    const int tid  = threadIdx.x;
    const int lane = tid & 63;
    const int w    = tid >> 6;
    const long row0 = (long)blockIdx.x * ROWS_PER_BLOCK;
    const int wr0  = w * 4;  // wave's first local row

    // ---------------- Phase A ----------------
    float acc[4][16];
    #pragma unroll
    for (int rr = 0; rr < 4; ++rr)
        #pragma unroll
        for (int r = 0; r < 16; ++r) acc[rr][r] = 0.0f;

    const float4* x4 = (const float4*)x;
    const long xbase = (row0 + wr0) * (D_IN / 4);

    for (int k = 0; k < 16; ++k) {
        const int p = lane + (k << 6);   // float4 column index, 0..1023
        float4 xv[4];
        #pragma unroll
        for (int rr = 0; rr < 4; ++rr)
            xv[rr] = x4[xbase + (long)rr * (D_IN / 4) + p];

        #pragma unroll
        for (int dd = 0; dd < 4; ++dd) {
            // W_a row for d = 4p+dd : 16 floats = one 64B line
            const float4* war = (const float4*)(Wa + ((size_t)(4 * p + dd) << 4));
            const float4 w0 = war[0], w1 = war[1], w2 = war[2], w3 = war[3];
            #pragma unroll
            for (int rr = 0; rr < 4; ++rr) {
                const float xs = ((const float*)&xv[rr])[dd];
                acc[rr][0]  += xs * w0.x;  acc[rr][1]  += xs * w0.y;
                acc[rr][2]  += xs * w0.z;  acc[rr][3]  += xs * w0.w;
                acc[rr][4]  += xs * w1.x;  acc[rr][5]  += xs * w1.y;
                acc[rr][6]  += xs * w1.z;  acc[rr][7]  += xs * w1.w;
                acc[rr][8]  += xs * w2.x;  acc[rr][9]  += xs * w2.y;
                acc[rr][10] += xs * w2.z;  acc[rr][11] += xs * w2.w;
                acc[rr][12] += xs * w3.x;  acc[rr][13] += xs * w3.y;
                acc[rr][14] += xs * w3.z;  acc[rr][15] += xs * w3.w;
            }
        }
    }

    // partial cross-lane reduce: lanes {4i..4i+3} -> lane 4i holds 4-lane sum
    #pragma unroll
    for (int rr = 0; rr < 4; ++rr)
        #pragma unroll
        for (int r = 0; r < 16; ++r) {
            float v = acc[rr][r];
            v += __shfl_xor(v, 1, 64);
            v += __shfl_xor(v, 2, 64);
            acc[rr][r] = v;
        }
    if ((lane & 3) == 0) {
        const int li = lane >> 2;  // 0..15 partial index
        #pragma unroll
        for (int rr = 0; rr < 4; ++rr)
            #pragma unroll
            for (int r = 0; r < 16; ++r)
                red[w][li][rr * 16 + r] = acc[rr][r];
    }
    __syncthreads();

    // ---------------- Stage 2 (thread t = (row = t>>4, r = t&15)) ----------
    {
        const int row  = tid >> 4;
        const int r    = tid & 15;
        const int w2   = tid >> 6;
        const int slot = tid & 63;
        float s = 0.0f;
        #pragma unroll
        for (int i = 0; i < 16; ++i) s += red[w2][i][slot];
        lds_nx[row][r] = s;
        __syncthreads();

        const float* hrow = h_t + (row0 + row) * RNK;
        float h1 = hrow[r];  // the "+ h_t" term
        #pragma unroll
        for (int j = 0; j < 16; ++j)
            h1 += hrow[j] * Wc[j * 16 + r] + lds_nx[row][j] * Wd[j * 16 + r];

        // min/max over the 16 threads of this row (xor masks < 16 stay in-group)
        float mn = h1, mx = h1;
        #pragma unroll
        for (int m = 1; m <= 8; m <<= 1) {
            mn = fminf(mn, __shfl_xor(mn, m, 64));
            mx = fmaxf(mx, __shfl_xor(mx, m, 64));
        }
        const float hn = (h1 - mn) / (mx - mn + EPS_F);
        const float a  = (hn >= 0.0f) ? hn : NEG_SLOPE_F * hn;
        lds_u[row][r] = ALPHA_F * (s + a);   // fold ALPHA here
    }
    __syncthreads();

    // ---------------- Phase B ----------------
    float4 uu[4][4];
    #pragma unroll
    for (int rr = 0; rr < 4; ++rr)
        #pragma unroll
        for (int j = 0; j < 4; ++j)
            uu[rr][j] = ((const float4*)lds_u[wr0 + rr])[j];

    const float4* Wb4 = (const float4*)Wb;    // [16][1024] float4
    float4* y4 = (float4*)y;
    const long ybase = (row0 + wr0) * (D_OUT / 4);

    for (int k = 0; k < 16; ++k) {
        const int p = lane + (k << 6);
        float4 wb[16];
        #pragma unroll
        for (int r2 = 0; r2 < 16; ++r2) wb[r2] = Wb4[(size_t)r2 * 1024 + p];
        #pragma unroll
        for (int rr = 0; rr < 4; ++rr) {
            float4 o; o.x = 0.0f; o.y = 0.0f; o.z = 0.0f; o.w = 0.0f;
            #pragma unroll
            for (int r2 = 0; r2 < 16; ++r2) {
                const float us = ((const float*)&uu[rr][0])[r2];
                o.x += us * wb[r2].x;
                o.y += us * wb[r2].y;
                o.z += us * wb[r2].z;
                o.w += us * wb[r2].w;
            }
            y4[ybase + (long)rr * (D_OUT / 4) + p] = o;
        }
    }
}

extern "C" void kernel_launch(void* const* d_in, const int* in_sizes, int n_in,
                              void* d_out, int out_size, void* d_ws, size_t ws_size,
                              hipStream_t stream) {
    const float* x   = (const float*)d_in[0];
    const float* h_t = (const float*)d_in[1];
    const float* Wa  = (const float*)d_in[2];
    const float* Wb  = (const float*)d_in[3];
    const float* Wc  = (const float*)d_in[4];
    const float* Wd  = (const float*)d_in[5];
    float* y = (float*)d_out;

    dim3 grid(N_ROWS / ROWS_PER_BLOCK);
    dim3 block(THREADS);
    ssm_lora_fused<<<grid, block, 0, stream>>>(x, h_t, Wa, Wb, Wc, Wd, y);
}